// Round 1
// baseline (116.560 us; speedup 1.0000x reference)
//
#include <hip/hip_runtime.h>
#include <hip/hip_bf16.h>
#include <cstdint>
#include <cstddef>

// Sizes (fixed by the problem)
#define BB 4
#define WW 20
#define MM 512
#define RNN_HID 64
#define HALF 32
#define KK 10
#define LONG_K 10
#define LONG_OUT 2
#define N_SPATIAL 10
#define NSEQ (BB*MM)   // 2048

// ---------------- ws layout (floats) ----------------
#define OFF_P     0            // 2048*32
#define OFF_QB    65536        // 2048*32
#define OFF_G1    131072       // 2048*64
#define OFF_TDOT  262144       // 2048
#define OFF_COLSQ 264192       // 2048 (reused as inv-norm)
#define OFF_AMX   266240       // 4*512*512
#define OFF_A     1314816      // 4*512*512
#define OFF_Z     2363392      // 2048*10

// ============ K1: RNN + p/q + convs + G1 + temporal dot ============
__global__ __launch_bounds__(256) void k1_rnn(
    const float* __restrict__ x, const float* __restrict__ W_ih,
    const float* __restrict__ W_hh, const float* __restrict__ b_ih,
    const float* __restrict__ b_hh, const float* __restrict__ W1,
    const float* __restrict__ b1, const float* __restrict__ W2,
    const float* __restrict__ conv_w, const float* __restrict__ conv_b,
    const float* __restrict__ convl_w, const float* __restrict__ convl_b,
    const float* __restrict__ gc1_w, const float* __restrict__ out_w,
    const float* __restrict__ out_b,
    float* __restrict__ p_out, float* __restrict__ qb_out,
    float* __restrict__ G1, float* __restrict__ tdot)
{
    __shared__ float h_sh[4][64];
    __shared__ float xt_sh[4][20];
    __shared__ float rl_sh[4][30];
    int tid = threadIdx.x;
    int w = tid >> 6, lane = tid & 63;
    int s = blockIdx.x * 4 + w;       // sequence id, 0..2047
    int b = s >> 9, m = s & 511;

    if (lane < 20) xt_sh[w][lane] = x[(b*20 + lane)*512 + m];

    float wrow[64];
    const float* wr = W_hh + lane*64;
    #pragma unroll
    for (int k4 = 0; k4 < 16; ++k4) {
        float4 v = reinterpret_cast<const float4*>(wr)[k4];
        wrow[4*k4+0]=v.x; wrow[4*k4+1]=v.y; wrow[4*k4+2]=v.z; wrow[4*k4+3]=v.w;
    }
    float wih = W_ih[lane], bih = b_ih[lane], bhh = b_hh[lane];
    h_sh[w][lane] = 0.f;
    float h = 0.f;
    __syncthreads();

    for (int t = 0; t < 20; ++t) {
        float acc = xt_sh[w][t]*wih + bih + bhh;
        #pragma unroll
        for (int k = 0; k < 64; ++k) acc += wrow[k]*h_sh[w][k];
        h = tanhf(acc);
        __syncthreads();
        h_sh[w][lane] = h;
        __syncthreads();
    }

    // temporal part of output head (+ out_b folded here)
    float td = h * out_w[10 + lane];
    #pragma unroll
    for (int off = 32; off; off >>= 1) td += __shfl_down(td, off);
    if (lane == 0) tdot[s] = td + out_b[0];

    // p (lanes 0..31) / q+b1 (lanes 32..63)
    if (lane < 32) {
        const float* w1r = W1 + lane*64;
        float acc = 0.f;
        #pragma unroll
        for (int k = 0; k < 64; ++k) acc += w1r[k]*h_sh[w][k];
        p_out[s*32 + lane] = acc;
    } else {
        int i = lane - 32;
        const float* w2r = W2 + i*64;
        float acc = 0.f;
        #pragma unroll
        for (int k = 0; k < 64; ++k) acc += w2r[k]*h_sh[w][k];
        qb_out[s*32 + i] = acc + b1[i];
    }

    // convs -> relu(r_l) in LDS
    if (lane < 10) {
        float acc = conv_b[lane];
        #pragma unroll
        for (int t = 0; t < 20; ++t) acc += conv_w[lane*20+t]*xt_sh[w][t];
        rl_sh[w][3*lane] = fmaxf(acc, 0.f);
    } else if (lane < 30) {
        int idx = lane-10, j = idx>>1, oo = idx&1;
        float acc = convl_b[j];
        #pragma unroll
        for (int t = 0; t < 10; ++t) acc += convl_w[j*10+t]*xt_sh[w][oo+2*t];
        rl_sh[w][3*j+1+oo] = fmaxf(acc, 0.f);
    }
    __syncthreads();

    // G1 = relu(r_l) @ gc1_w   (30 x 64)
    float g = 0.f;
    #pragma unroll
    for (int t = 0; t < 30; ++t) g += rl_sh[w][t]*gc1_w[t*64 + lane];
    G1[s*64 + lane] = g;
}

// ============ K2a: a_mx = V . elu(p_i + qb_j) + bv ; column sumsq ============
__global__ __launch_bounds__(256) void k2_amx(
    const float* __restrict__ p, const float* __restrict__ qb,
    const float* __restrict__ V, const float* __restrict__ bv,
    float* __restrict__ amx, float* __restrict__ colsq)
{
    __shared__ float p_sh[16*33], q_sh[16*33], v_sh[32], sq_sh[16*17];
    int t = threadIdx.x;
    int b = blockIdx.z, i0 = blockIdx.y*16, j0 = blockIdx.x*16;
    {
        int r = t >> 5, cc = t & 31;
        p_sh[r*33+cc]     = p [(b*512 + i0 + r   )*32 + cc];
        q_sh[r*33+cc]     = qb[(b*512 + j0 + r   )*32 + cc];
        p_sh[(r+8)*33+cc] = p [(b*512 + i0 + r+8 )*32 + cc];
        q_sh[(r+8)*33+cc] = qb[(b*512 + j0 + r+8 )*32 + cc];
    }
    if (t < 32) v_sh[t] = V[t];
    __syncthreads();

    int ti = t >> 4, tj = t & 15;
    float acc = bv[0];
    #pragma unroll
    for (int h = 0; h < 32; ++h) {
        float xv = p_sh[ti*33+h] + q_sh[tj*33+h];
        float e = xv > 0.f ? xv : expm1f(xv);
        acc += v_sh[h]*e;
    }
    amx[((size_t)(b*512 + i0+ti))*512 + j0 + tj] = acc;

    sq_sh[ti*17+tj] = acc*acc;
    __syncthreads();
    if (ti == 0) {
        float ssum = 0.f;
        #pragma unroll
        for (int r = 0; r < 16; ++r) ssum += sq_sh[r*17+tj];
        atomicAdd(&colsq[b*512 + j0 + tj], ssum);
    }
}

// ============ K2b: invn = 1/max(sqrt(colsq),1e-12) (in place) ============
__global__ void k2b_invn(float* __restrict__ colsq)
{
    int i = blockIdx.x*256 + threadIdx.x;
    if (i < 2048) {
        float n = fmaxf(sqrtf(colsq[i]), 1e-12f);
        colsq[i] = 1.f/n;
    }
}

// ============ K2c: amx[b,i,j] *= invn[b,j] ============
__global__ void k2c_norm(float* __restrict__ amx, const float* __restrict__ invn)
{
    int idx = blockIdx.x*256 + threadIdx.x;   // < 2^20
    int j = idx & 511, b = idx >> 18;
    amx[idx] *= invn[b*512 + j];
}

// ============ K3a: S = amxN @ Wb ; c=sigmoid(S+wb); A = adj*c + amxN*(1-c) ============
__global__ __launch_bounds__(256) void k3a_wb(
    const float* __restrict__ amxN, const float* __restrict__ Wb,
    const float* __restrict__ wb, const float* __restrict__ adj,
    float* __restrict__ A)
{
    __shared__ float As[16][64];   // k-major
    __shared__ float Bs[16][64];
    int t = threadIdx.x;
    int b = blockIdx.z;
    int i0 = blockIdx.y*64, j0 = blockIdx.x*64;
    int tx = t & 15, ty = t >> 4;
    float acc[4][4] = {};
    const float* Abase = amxN + ((size_t)(b*512 + i0))*512;

    int lr  = t & 63;          // A row 0..63
    int lk4 = (t >> 6)*4;      // A k chunk
    int bk  = t >> 4;          // B kk 0..15
    int bj4 = (t & 15)*4;      // B j chunk

    for (int k0 = 0; k0 < 512; k0 += 16) {
        float4 av  = *reinterpret_cast<const float4*>(Abase + (size_t)lr*512 + k0 + lk4);
        float4 bv4 = *reinterpret_cast<const float4*>(Wb + (size_t)(k0+bk)*512 + j0 + bj4);
        As[lk4+0][lr]=av.x; As[lk4+1][lr]=av.y; As[lk4+2][lr]=av.z; As[lk4+3][lr]=av.w;
        *reinterpret_cast<float4*>(&Bs[bk][bj4]) = bv4;
        __syncthreads();
        #pragma unroll
        for (int kk = 0; kk < 16; ++kk) {
            float4 a4 = *reinterpret_cast<const float4*>(&As[kk][4*ty]);
            float4 b4 = *reinterpret_cast<const float4*>(&Bs[kk][4*tx]);
            float av_[4] = {a4.x,a4.y,a4.z,a4.w};
            float bv_[4] = {b4.x,b4.y,b4.z,b4.w};
            #pragma unroll
            for (int ri = 0; ri < 4; ++ri)
                #pragma unroll
                for (int ci = 0; ci < 4; ++ci)
                    acc[ri][ci] += av_[ri]*bv_[ci];
        }
        __syncthreads();
    }

    float wbs = wb[0];
    #pragma unroll
    for (int ri = 0; ri < 4; ++ri) {
        int i = i0 + 4*ty + ri;
        #pragma unroll
        for (int ci = 0; ci < 4; ++ci) {
            int j = j0 + 4*tx + ci;
            float S = acc[ri][ci] + wbs;
            float c = 1.f/(1.f + __expf(-S));
            float aN = amxN[((size_t)(b*512+i))*512 + j];
            A[((size_t)(b*512+i))*512 + j] = adj[i*512+j]*c + aN*(1.f - c);
        }
    }
}

// ============ K3b: xg = relu(A@G1 + gc1_b); z = xg@gc2_w ============
__global__ __launch_bounds__(256) void k3b_xg_z(
    const float* __restrict__ A, const float* __restrict__ G1,
    const float* __restrict__ gc1_b, const float* __restrict__ gc2_w,
    float* __restrict__ z)
{
    __shared__ float As[16][68];
    __shared__ float Gs[64][64];
    __shared__ float xg_sh[16][68];
    int t = threadIdx.x;
    int b = blockIdx.y, i0 = blockIdx.x*16;
    int tx = t & 63, ty = t >> 6;   // tx = k, ty = 0..3
    float acc[4] = {};

    for (int jc = 0; jc < 8; ++jc) {
        int j0 = jc*64;
        {
            int r = t >> 4, c4 = (t & 15)*4;
            *reinterpret_cast<float4*>(&As[r][c4]) =
                *reinterpret_cast<const float4*>(A + ((size_t)(b*512 + i0 + r))*512 + j0 + c4);
            #pragma unroll
            for (int q = 0; q < 4; ++q) {
                int rr = r + 16*q;
                *reinterpret_cast<float4*>(&Gs[rr][c4]) =
                    *reinterpret_cast<const float4*>(G1 + (size_t)(b*512 + j0 + rr)*64 + c4);
            }
        }
        __syncthreads();
        #pragma unroll 16
        for (int jj = 0; jj < 64; ++jj) {
            float g = Gs[jj][tx];
            #pragma unroll
            for (int q = 0; q < 4; ++q) acc[q] += As[ty + 4*q][jj]*g;
        }
        __syncthreads();
    }

    #pragma unroll
    for (int q = 0; q < 4; ++q)
        xg_sh[ty + 4*q][tx] = fmaxf(acc[q] + gc1_b[tx], 0.f);
    __syncthreads();

    if (t < 160) {
        int i = t/10, sx = t%10;
        float val = 0.f;
        #pragma unroll
        for (int k = 0; k < 64; ++k) val += xg_sh[i][k]*gc2_w[k*10 + sx];
        z[((size_t)(b*512) + i0 + i)*10 + sx] = val;
    }
}

// ============ K4: out = relu(A@z + gc2_b).out_w_s + tdot ============
__global__ __launch_bounds__(256) void k4_out(
    const float* __restrict__ A, const float* __restrict__ z,
    const float* __restrict__ gc2_b, const float* __restrict__ out_w,
    const float* __restrict__ tdot, float* __restrict__ out)
{
    int t = threadIdx.x;
    int w = t >> 6, lane = t & 63;
    int s = blockIdx.x*4 + w;       // (b,i)
    int b = s >> 9;
    const float* Arow = A + (size_t)s*512;
    float acc[10] = {};
    #pragma unroll
    for (int jj = 0; jj < 8; ++jj) {
        int j = jj*64 + lane;
        float a = Arow[j];
        const float* zr = z + (size_t)(b*512 + j)*10;
        #pragma unroll
        for (int sx = 0; sx < 10; ++sx) acc[sx] += a*zr[sx];
    }
    #pragma unroll
    for (int sx = 0; sx < 10; ++sx)
        #pragma unroll
        for (int off = 32; off; off >>= 1) acc[sx] += __shfl_down(acc[sx], off);
    if (lane == 0) {
        float o = tdot[s];
        #pragma unroll
        for (int sx = 0; sx < 10; ++sx)
            o += fmaxf(acc[sx] + gc2_b[sx], 0.f) * out_w[sx];
        out[s] = o;
    }
}

extern "C" void kernel_launch(void* const* d_in, const int* in_sizes, int n_in,
                              void* d_out, int out_size, void* d_ws, size_t ws_size,
                              hipStream_t stream) {
    const float* x       = (const float*)d_in[0];
    const float* W_ih    = (const float*)d_in[1];
    const float* W_hh    = (const float*)d_in[2];
    const float* b_ih    = (const float*)d_in[3];
    const float* b_hh    = (const float*)d_in[4];
    const float* W1      = (const float*)d_in[5];
    const float* b1      = (const float*)d_in[6];
    const float* W2      = (const float*)d_in[7];
    const float* V       = (const float*)d_in[8];
    const float* bv      = (const float*)d_in[9];
    const float* Wb      = (const float*)d_in[10];
    const float* wb      = (const float*)d_in[11];
    const float* conv_w  = (const float*)d_in[12];
    const float* conv_b  = (const float*)d_in[13];
    const float* convl_w = (const float*)d_in[14];
    const float* convl_b = (const float*)d_in[15];
    const float* gc1_w   = (const float*)d_in[16];
    const float* gc1_b   = (const float*)d_in[17];
    const float* gc2_w   = (const float*)d_in[18];
    const float* gc2_b   = (const float*)d_in[19];
    const float* out_w   = (const float*)d_in[20];
    const float* out_b   = (const float*)d_in[21];
    const float* adj     = (const float*)d_in[22];

    float* ws    = (float*)d_ws;
    float* p     = ws + OFF_P;
    float* qb    = ws + OFF_QB;
    float* G1    = ws + OFF_G1;
    float* tdot  = ws + OFF_TDOT;
    float* colsq = ws + OFF_COLSQ;
    float* amx   = ws + OFF_AMX;
    float* A     = ws + OFF_A;
    float* z     = ws + OFF_Z;
    float* out   = (float*)d_out;

    hipMemsetAsync(colsq, 0, 2048*sizeof(float), stream);

    k1_rnn<<<dim3(512), dim3(256), 0, stream>>>(
        x, W_ih, W_hh, b_ih, b_hh, W1, b1, W2,
        conv_w, conv_b, convl_w, convl_b, gc1_w, out_w, out_b,
        p, qb, G1, tdot);

    k2_amx<<<dim3(32,32,4), dim3(256), 0, stream>>>(p, qb, V, bv, amx, colsq);
    k2b_invn<<<dim3(8), dim3(256), 0, stream>>>(colsq);
    k2c_norm<<<dim3(4096), dim3(256), 0, stream>>>(amx, colsq);

    k3a_wb<<<dim3(8,8,4), dim3(256), 0, stream>>>(amx, Wb, wb, adj, A);
    k3b_xg_z<<<dim3(32,4), dim3(256), 0, stream>>>(A, G1, gc1_b, gc2_w, z);
    k4_out<<<dim3(512), dim3(256), 0, stream>>>(A, z, gc2_b, out_w, tdot, out);
}

// Round 2
// 89.266 us; speedup vs baseline: 1.3058x; 1.3058x over previous
//
#include <hip/hip_runtime.h>
#include <hip/hip_bf16.h>
#include <cstdint>
#include <cstddef>

// Sizes (fixed by the problem)
#define BB 4
#define WW 20
#define MM 512
#define RNN_HID 64
#define HALF 32
#define N_SPATIAL 10

// ---------------- ws layout (float slots) ----------------
#define OFF_P     0            // 2048*32
#define OFF_QB    65536        // 2048*32
#define OFF_G1    131072       // 2048*64
#define OFF_TDOT  262144       // 2048
#define OFF_COLSQ 264192       // 2048 (becomes inv-norm in k2b)
#define OFF_AMX   266240       // 4*512*512 f32
#define OFF_A     1314816      // 4*512*512 f32
#define OFF_Z     2363392      // 2048*10
#define OFF_AMXB  2383872      // 4*512*512 bf16 (524288 float slots)
#define OFF_WBT   2908160      // 4*512*512 bf16 (524288 float slots)

typedef __attribute__((ext_vector_type(8))) short short8;
typedef __attribute__((ext_vector_type(8))) unsigned short ushort8;
typedef __attribute__((ext_vector_type(4))) float f32x4;

__device__ inline unsigned short f2bf(float f) {
    unsigned u = __builtin_bit_cast(unsigned, f);
    unsigned r = u + 0x7FFFu + ((u >> 16) & 1u);
    return (unsigned short)(r >> 16);
}

// ============ K1: RNN + p/q + convs + G1 + temporal dot (+ zero colsq) ============
__global__ __launch_bounds__(256) void k1_rnn(
    const float* __restrict__ x, const float* __restrict__ W_ih,
    const float* __restrict__ W_hh, const float* __restrict__ b_ih,
    const float* __restrict__ b_hh, const float* __restrict__ W1,
    const float* __restrict__ b1, const float* __restrict__ W2,
    const float* __restrict__ conv_w, const float* __restrict__ conv_b,
    const float* __restrict__ convl_w, const float* __restrict__ convl_b,
    const float* __restrict__ gc1_w, const float* __restrict__ out_w,
    const float* __restrict__ out_b,
    float* __restrict__ p_out, float* __restrict__ qb_out,
    float* __restrict__ G1, float* __restrict__ tdot,
    float* __restrict__ colsq)
{
    __shared__ float h_sh[4][64];
    __shared__ float xt_sh[4][20];
    __shared__ float rl_sh[4][30];
    int tid = threadIdx.x;
    int w = tid >> 6, lane = tid & 63;
    int s = blockIdx.x * 4 + w;       // sequence id, 0..2047
    int b = s >> 9, m = s & 511;

    if (blockIdx.x < 8) colsq[blockIdx.x * 256 + tid] = 0.f;   // replaces memset

    if (lane < 20) xt_sh[w][lane] = x[(b*20 + lane)*512 + m];

    float wrow[64];
    const float* wr = W_hh + lane*64;
    #pragma unroll
    for (int k4 = 0; k4 < 16; ++k4) {
        float4 v = reinterpret_cast<const float4*>(wr)[k4];
        wrow[4*k4+0]=v.x; wrow[4*k4+1]=v.y; wrow[4*k4+2]=v.z; wrow[4*k4+3]=v.w;
    }
    float wih = W_ih[lane], bih = b_ih[lane], bhh = b_hh[lane];
    h_sh[w][lane] = 0.f;
    float h = 0.f;
    __syncthreads();

    for (int t = 0; t < 20; ++t) {
        float acc = xt_sh[w][t]*wih + bih + bhh;
        #pragma unroll
        for (int k = 0; k < 64; ++k) acc += wrow[k]*h_sh[w][k];
        h = tanhf(acc);
        __syncthreads();
        h_sh[w][lane] = h;
        __syncthreads();
    }

    // temporal part of output head (+ out_b folded here)
    float td = h * out_w[10 + lane];
    #pragma unroll
    for (int off = 32; off; off >>= 1) td += __shfl_down(td, off);
    if (lane == 0) tdot[s] = td + out_b[0];

    // p (lanes 0..31) / q+b1 (lanes 32..63)
    if (lane < 32) {
        const float* w1r = W1 + lane*64;
        float acc = 0.f;
        #pragma unroll
        for (int k = 0; k < 64; ++k) acc += w1r[k]*h_sh[w][k];
        p_out[s*32 + lane] = acc;
    } else {
        int i = lane - 32;
        const float* w2r = W2 + i*64;
        float acc = 0.f;
        #pragma unroll
        for (int k = 0; k < 64; ++k) acc += w2r[k]*h_sh[w][k];
        qb_out[s*32 + i] = acc + b1[i];
    }

    // convs -> relu(r_l) in LDS
    if (lane < 10) {
        float acc = conv_b[lane];
        #pragma unroll
        for (int t = 0; t < 20; ++t) acc += conv_w[lane*20+t]*xt_sh[w][t];
        rl_sh[w][3*lane] = fmaxf(acc, 0.f);
    } else if (lane < 30) {
        int idx = lane-10, j = idx>>1, oo = idx&1;
        float acc = convl_b[j];
        #pragma unroll
        for (int t = 0; t < 10; ++t) acc += convl_w[j*10+t]*xt_sh[w][oo+2*t];
        rl_sh[w][3*j+1+oo] = fmaxf(acc, 0.f);
    }
    __syncthreads();

    // G1 = relu(r_l) @ gc1_w   (30 x 64)
    float g = 0.f;
    #pragma unroll
    for (int t = 0; t < 30; ++t) g += rl_sh[w][t]*gc1_w[t*64 + lane];
    G1[s*64 + lane] = g;
}

// ============ K2a: a_mx = V . elu(p_i + qb_j) + bv ; bf16 copy ; column sumsq ============
__global__ __launch_bounds__(256) void k2_amx(
    const float* __restrict__ p, const float* __restrict__ qb,
    const float* __restrict__ V, const float* __restrict__ bv,
    float* __restrict__ amx, unsigned short* __restrict__ amxB,
    float* __restrict__ colsq)
{
    __shared__ float p_sh[16*33], q_sh[16*33], v_sh[32], sq_sh[16*17];
    int t = threadIdx.x;
    int b = blockIdx.z, i0 = blockIdx.y*16, j0 = blockIdx.x*16;
    {
        int r = t >> 5, cc = t & 31;
        p_sh[r*33+cc]     = p [(b*512 + i0 + r   )*32 + cc];
        q_sh[r*33+cc]     = qb[(b*512 + j0 + r   )*32 + cc];
        p_sh[(r+8)*33+cc] = p [(b*512 + i0 + r+8 )*32 + cc];
        q_sh[(r+8)*33+cc] = qb[(b*512 + j0 + r+8 )*32 + cc];
    }
    if (t < 32) v_sh[t] = V[t];
    __syncthreads();

    int ti = t >> 4, tj = t & 15;
    float acc = bv[0];
    #pragma unroll
    for (int h = 0; h < 32; ++h) {
        float xv = p_sh[ti*33+h] + q_sh[tj*33+h];
        float e = xv > 0.f ? xv : expm1f(xv);
        acc += v_sh[h]*e;
    }
    size_t ofs = ((size_t)(b*512 + i0+ti))*512 + j0 + tj;
    amx[ofs] = acc;
    amxB[ofs] = f2bf(acc);

    sq_sh[ti*17+tj] = acc*acc;
    __syncthreads();
    if (ti == 0) {
        float ssum = 0.f;
        #pragma unroll
        for (int r = 0; r < 16; ++r) ssum += sq_sh[r*17+tj];
        atomicAdd(&colsq[b*512 + j0 + tj], ssum);
    }
}

// ============ K2b: invn = 1/max(sqrt(colsq),1e-12) (in place) ============
__global__ void k2b_invn(float* __restrict__ colsq)
{
    int i = blockIdx.x*256 + threadIdx.x;
    if (i < 2048) {
        float n = fmaxf(sqrtf(colsq[i]), 1e-12f);
        colsq[i] = 1.f/n;
    }
}

// ============ K2w: WbT[b][j][k] = bf16(Wb[k][j] * invn[b][k]) ============
__global__ __launch_bounds__(256) void k2w_scale(
    const float* __restrict__ Wb, const float* __restrict__ invn,
    unsigned short* __restrict__ WbT)
{
    __shared__ float tile[64][68];
    int t = threadIdx.x;
    int j0 = blockIdx.x*64, k0 = blockIdx.y*64;
    #pragma unroll
    for (int q = 0; q < 4; ++q) {
        int kr = (t>>4) + 16*q;
        int jc = (t&15)*4;
        *(float4*)&tile[kr][jc] = *(const float4*)(Wb + (size_t)(k0+kr)*512 + j0 + jc);
    }
    __syncthreads();
    int jl = t>>2, kc = (t&3)*16;
    int j = j0 + jl;
    for (int b = 0; b < 4; ++b) {
        ushort8 v0, v1;
        #pragma unroll
        for (int kk = 0; kk < 8; ++kk)
            v0[kk] = f2bf(tile[kc+kk][jl] * invn[b*512 + k0+kc+kk]);
        #pragma unroll
        for (int kk = 0; kk < 8; ++kk)
            v1[kk] = f2bf(tile[kc+8+kk][jl] * invn[b*512 + k0+kc+8+kk]);
        unsigned short* dst = WbT + ((size_t)(b*512 + j))*512 + k0 + kc;
        *(ushort8*)dst = v0;
        *(ushort8*)(dst+8) = v1;
    }
}

// ============ K3a: S = (amx@diag(invn))@Wb via bf16 MFMA; gate epilogue ============
__global__ __launch_bounds__(256) void k3a_mfma(
    const unsigned short* __restrict__ amxB, const unsigned short* __restrict__ WbT,
    const float* __restrict__ amx, const float* __restrict__ invn,
    const float* __restrict__ wb, const float* __restrict__ adj,
    float* __restrict__ A)
{
    __shared__ __align__(16) unsigned short As[64*72];   // [row i][k], pad 72
    __shared__ __align__(16) unsigned short Bs[64*72];   // [col j][k], pad 72
    int t = threadIdx.x;
    int b = blockIdx.z;
    int i0 = blockIdx.y*64, j0 = blockIdx.x*64;
    int wv = t >> 6, lane = t & 63;
    int wr = (wv>>1)*32, wc = (wv&1)*32;
    f32x4 acc[2][2] = {};

    int srow = t >> 2, skc = (t&3)*16;
    const unsigned short* ag = amxB + ((size_t)(b*512 + i0 + srow))*512 + skc;
    const unsigned short* bg = WbT  + ((size_t)(b*512 + j0 + srow))*512 + skc;
    unsigned short* asl = &As[srow*72 + skc];
    unsigned short* bsl = &Bs[srow*72 + skc];

    for (int k0 = 0; k0 < 512; k0 += 64) {
        short8 a0 = *(const short8*)(ag + k0);
        short8 a1 = *(const short8*)(ag + k0 + 8);
        short8 b0 = *(const short8*)(bg + k0);
        short8 b1 = *(const short8*)(bg + k0 + 8);
        *(short8*)asl = a0; *(short8*)(asl+8) = a1;
        *(short8*)bsl = b0; *(short8*)(bsl+8) = b1;
        __syncthreads();
        #pragma unroll
        for (int h = 0; h < 2; ++h) {
            int kk = h*32 + (lane>>4)*8;
            short8 af0 = *(const short8*)&As[(wr +      (lane&15))*72 + kk];
            short8 af1 = *(const short8*)&As[(wr + 16 + (lane&15))*72 + kk];
            short8 bf0 = *(const short8*)&Bs[(wc +      (lane&15))*72 + kk];
            short8 bf1 = *(const short8*)&Bs[(wc + 16 + (lane&15))*72 + kk];
            acc[0][0] = __builtin_amdgcn_mfma_f32_16x16x32_bf16(af0, bf0, acc[0][0],0,0,0);
            acc[0][1] = __builtin_amdgcn_mfma_f32_16x16x32_bf16(af0, bf1, acc[0][1],0,0,0);
            acc[1][0] = __builtin_amdgcn_mfma_f32_16x16x32_bf16(af1, bf0, acc[1][0],0,0,0);
            acc[1][1] = __builtin_amdgcn_mfma_f32_16x16x32_bf16(af1, bf1, acc[1][1],0,0,0);
        }
        __syncthreads();
    }

    float wbs = wb[0];
    #pragma unroll
    for (int fi = 0; fi < 2; ++fi)
    #pragma unroll
    for (int fj = 0; fj < 2; ++fj)
    #pragma unroll
    for (int r = 0; r < 4; ++r) {
        int i = i0 + wr + fi*16 + (lane>>4)*4 + r;
        int j = j0 + wc + fj*16 + (lane&15);
        float S = acc[fi][fj][r] + wbs;
        float c = 1.f/(1.f + __expf(-S));
        float aN = amx[((size_t)(b*512)+i)*512 + j] * invn[b*512 + j];
        A[((size_t)(b*512)+i)*512 + j] = adj[i*512+j]*c + aN*(1.f - c);
    }
}

// ============ K3b: xg = relu(A@G1 + gc1_b); z = xg@gc2_w ============
__global__ __launch_bounds__(256) void k3b_xg_z(
    const float* __restrict__ A, const float* __restrict__ G1,
    const float* __restrict__ gc1_b, const float* __restrict__ gc2_w,
    float* __restrict__ z)
{
    __shared__ float As[16][68];
    __shared__ float Gs[64][64];
    __shared__ float xg_sh[16][68];
    int t = threadIdx.x;
    int b = blockIdx.y, i0 = blockIdx.x*16;
    int tx = t & 63, ty = t >> 6;   // tx = k, ty = 0..3
    float acc[4] = {};

    for (int jc = 0; jc < 8; ++jc) {
        int j0 = jc*64;
        {
            int r = t >> 4, c4 = (t & 15)*4;
            *reinterpret_cast<float4*>(&As[r][c4]) =
                *reinterpret_cast<const float4*>(A + ((size_t)(b*512 + i0 + r))*512 + j0 + c4);
            #pragma unroll
            for (int q = 0; q < 4; ++q) {
                int rr = r + 16*q;
                *reinterpret_cast<float4*>(&Gs[rr][c4]) =
                    *reinterpret_cast<const float4*>(G1 + (size_t)(b*512 + j0 + rr)*64 + c4);
            }
        }
        __syncthreads();
        #pragma unroll 16
        for (int jj = 0; jj < 64; ++jj) {
            float g = Gs[jj][tx];
            #pragma unroll
            for (int q = 0; q < 4; ++q) acc[q] += As[ty + 4*q][jj]*g;
        }
        __syncthreads();
    }

    #pragma unroll
    for (int q = 0; q < 4; ++q)
        xg_sh[ty + 4*q][tx] = fmaxf(acc[q] + gc1_b[tx], 0.f);
    __syncthreads();

    if (t < 160) {
        int i = t/10, sx = t%10;
        float val = 0.f;
        #pragma unroll
        for (int k = 0; k < 64; ++k) val += xg_sh[i][k]*gc2_w[k*10 + sx];
        z[((size_t)(b*512) + i0 + i)*10 + sx] = val;
    }
}

// ============ K4: out = relu(A@z + gc2_b).out_w_s + tdot ============
__global__ __launch_bounds__(256) void k4_out(
    const float* __restrict__ A, const float* __restrict__ z,
    const float* __restrict__ gc2_b, const float* __restrict__ out_w,
    const float* __restrict__ tdot, float* __restrict__ out)
{
    int t = threadIdx.x;
    int w = t >> 6, lane = t & 63;
    int s = blockIdx.x*4 + w;       // (b,i)
    int b = s >> 9;
    const float* Arow = A + (size_t)s*512;
    float acc[10] = {};
    #pragma unroll
    for (int jj = 0; jj < 8; ++jj) {
        int j = jj*64 + lane;
        float a = Arow[j];
        const float* zr = z + (size_t)(b*512 + j)*10;
        #pragma unroll
        for (int sx = 0; sx < 10; ++sx) acc[sx] += a*zr[sx];
    }
    #pragma unroll
    for (int sx = 0; sx < 10; ++sx)
        #pragma unroll
        for (int off = 32; off; off >>= 1) acc[sx] += __shfl_down(acc[sx], off);
    if (lane == 0) {
        float o = tdot[s];
        #pragma unroll
        for (int sx = 0; sx < 10; ++sx)
            o += fmaxf(acc[sx] + gc2_b[sx], 0.f) * out_w[sx];
        out[s] = o;
    }
}

extern "C" void kernel_launch(void* const* d_in, const int* in_sizes, int n_in,
                              void* d_out, int out_size, void* d_ws, size_t ws_size,
                              hipStream_t stream) {
    const float* x       = (const float*)d_in[0];
    const float* W_ih    = (const float*)d_in[1];
    const float* W_hh    = (const float*)d_in[2];
    const float* b_ih    = (const float*)d_in[3];
    const float* b_hh    = (const float*)d_in[4];
    const float* W1      = (const float*)d_in[5];
    const float* b1      = (const float*)d_in[6];
    const float* W2      = (const float*)d_in[7];
    const float* V       = (const float*)d_in[8];
    const float* bv      = (const float*)d_in[9];
    const float* Wb      = (const float*)d_in[10];
    const float* wb      = (const float*)d_in[11];
    const float* conv_w  = (const float*)d_in[12];
    const float* conv_b  = (const float*)d_in[13];
    const float* convl_w = (const float*)d_in[14];
    const float* convl_b = (const float*)d_in[15];
    const float* gc1_w   = (const float*)d_in[16];
    const float* gc1_b   = (const float*)d_in[17];
    const float* gc2_w   = (const float*)d_in[18];
    const float* gc2_b   = (const float*)d_in[19];
    const float* out_w   = (const float*)d_in[20];
    const float* out_b   = (const float*)d_in[21];
    const float* adj     = (const float*)d_in[22];

    float* ws    = (float*)d_ws;
    float* p     = ws + OFF_P;
    float* qb    = ws + OFF_QB;
    float* G1    = ws + OFF_G1;
    float* tdot  = ws + OFF_TDOT;
    float* colsq = ws + OFF_COLSQ;
    float* amx   = ws + OFF_AMX;
    float* A     = ws + OFF_A;
    float* z     = ws + OFF_Z;
    unsigned short* amxB = (unsigned short*)(ws + OFF_AMXB);
    unsigned short* WbT  = (unsigned short*)(ws + OFF_WBT);
    float* out   = (float*)d_out;

    k1_rnn<<<dim3(512), dim3(256), 0, stream>>>(
        x, W_ih, W_hh, b_ih, b_hh, W1, b1, W2,
        conv_w, conv_b, convl_w, convl_b, gc1_w, out_w, out_b,
        p, qb, G1, tdot, colsq);

    k2_amx<<<dim3(32,32,4), dim3(256), 0, stream>>>(p, qb, V, bv, amx, amxB, colsq);
    k2b_invn<<<dim3(8), dim3(256), 0, stream>>>(colsq);
    k2w_scale<<<dim3(8,8), dim3(256), 0, stream>>>(Wb, colsq, WbT);

    k3a_mfma<<<dim3(8,8,4), dim3(256), 0, stream>>>(amxB, WbT, amx, colsq, wb, adj, A);
    k3b_xg_z<<<dim3(32,4), dim3(256), 0, stream>>>(A, G1, gc1_b, gc2_w, z);
    k4_out<<<dim3(512), dim3(256), 0, stream>>>(A, z, gc2_b, out_w, tdot, out);
}

// Round 3
// 68.745 us; speedup vs baseline: 1.6955x; 1.2985x over previous
//
#include <hip/hip_runtime.h>
#include <hip/hip_bf16.h>
#include <cstdint>
#include <cstddef>

// ---------------- ws layout (float slots) ----------------
#define OFF_P     0            // 2048*32 f32
#define OFF_QB    65536        // 2048*32 f32
#define OFF_TDOT  131072       // 2048 f32
#define OFF_COLSQ 133120       // 2048 f32
#define OFF_ZT    135168       // 4*10*512 f32
#define OFF_G1B   155648       // 2048*64 bf16 (65536 float slots)
#define OFF_AMXB  221184       // 4*512*512 bf16 (524288 float slots)
#define OFF_WBT   745472       // 4*512*512 bf16
#define OFF_ABF   1269760      // 4*512*512 bf16

typedef __attribute__((ext_vector_type(8))) short short8;
typedef __attribute__((ext_vector_type(8))) unsigned short ushort8;
typedef __attribute__((ext_vector_type(2))) unsigned short ushort2v;
typedef __attribute__((ext_vector_type(4))) float f32x4;

__device__ inline unsigned short f2bf(float f) {
    unsigned u = __builtin_bit_cast(unsigned, f);
    unsigned r = u + 0x7FFFu + ((u >> 16) & 1u);
    return (unsigned short)(r >> 16);
}
__device__ inline float bf2f(unsigned short s) {
    unsigned u = ((unsigned)s) << 16;
    return __builtin_bit_cast(float, u);
}
__device__ inline float tanh_fast(float x) {
    return 1.f - 2.f/(__expf(2.f*x) + 1.f);
}

// ============ K1: RNN + p/q + convs + G1(bf16) + temporal dot (+ zero colsq) ============
__global__ __launch_bounds__(256) void k1_rnn(
    const float* __restrict__ x, const float* __restrict__ W_ih,
    const float* __restrict__ W_hh, const float* __restrict__ b_ih,
    const float* __restrict__ b_hh, const float* __restrict__ W1,
    const float* __restrict__ b1, const float* __restrict__ W2,
    const float* __restrict__ conv_w, const float* __restrict__ conv_b,
    const float* __restrict__ convl_w, const float* __restrict__ convl_b,
    const float* __restrict__ gc1_w, const float* __restrict__ out_w,
    const float* __restrict__ out_b,
    float* __restrict__ p_out, float* __restrict__ qb_out,
    unsigned short* __restrict__ G1bf, float* __restrict__ tdot,
    float* __restrict__ colsq)
{
    __shared__ float h_sh[4][64];
    __shared__ float xt_sh[4][20];
    __shared__ float rl_sh[4][30];
    int tid = threadIdx.x;
    int w = tid >> 6, lane = tid & 63;
    int s = blockIdx.x * 4 + w;       // sequence id, 0..2047
    int b = s >> 9, m = s & 511;

    if (blockIdx.x < 8) colsq[blockIdx.x * 256 + tid] = 0.f;   // replaces memset

    if (lane < 20) xt_sh[w][lane] = x[(b*20 + lane)*512 + m];

    float wrow[64];
    const float* wr = W_hh + lane*64;
    #pragma unroll
    for (int k4 = 0; k4 < 16; ++k4) {
        float4 v = reinterpret_cast<const float4*>(wr)[k4];
        wrow[4*k4+0]=v.x; wrow[4*k4+1]=v.y; wrow[4*k4+2]=v.z; wrow[4*k4+3]=v.w;
    }
    float wih = W_ih[lane], bih = b_ih[lane], bhh = b_hh[lane];
    h_sh[w][lane] = 0.f;
    float h = 0.f;
    __syncthreads();

    for (int t = 0; t < 20; ++t) {
        float acc = xt_sh[w][t]*wih + bih + bhh;
        #pragma unroll
        for (int k = 0; k < 64; ++k) acc += wrow[k]*h_sh[w][k];
        h = tanh_fast(acc);
        __syncthreads();
        h_sh[w][lane] = h;
        __syncthreads();
    }

    // temporal part of output head (+ out_b folded here)
    float td = h * out_w[10 + lane];
    #pragma unroll
    for (int off = 32; off; off >>= 1) td += __shfl_down(td, off);
    if (lane == 0) tdot[s] = td + out_b[0];

    // p (lanes 0..31) / q+b1 (lanes 32..63)
    if (lane < 32) {
        const float* w1r = W1 + lane*64;
        float acc = 0.f;
        #pragma unroll
        for (int k = 0; k < 64; ++k) acc += w1r[k]*h_sh[w][k];
        p_out[s*32 + lane] = acc;
    } else {
        int i = lane - 32;
        const float* w2r = W2 + i*64;
        float acc = 0.f;
        #pragma unroll
        for (int k = 0; k < 64; ++k) acc += w2r[k]*h_sh[w][k];
        qb_out[s*32 + i] = acc + b1[i];
    }

    // convs -> relu(r_l) in LDS
    if (lane < 10) {
        float acc = conv_b[lane];
        #pragma unroll
        for (int t = 0; t < 20; ++t) acc += conv_w[lane*20+t]*xt_sh[w][t];
        rl_sh[w][3*lane] = fmaxf(acc, 0.f);
    } else if (lane < 30) {
        int idx = lane-10, j = idx>>1, oo = idx&1;
        float acc = convl_b[j];
        #pragma unroll
        for (int t = 0; t < 10; ++t) acc += convl_w[j*10+t]*xt_sh[w][oo+2*t];
        rl_sh[w][3*j+1+oo] = fmaxf(acc, 0.f);
    }
    __syncthreads();

    // G1 = relu(r_l) @ gc1_w   (30 x 64)  -> bf16
    float g = 0.f;
    #pragma unroll
    for (int t = 0; t < 30; ++t) g += rl_sh[w][t]*gc1_w[t*64 + lane];
    G1bf[s*64 + lane] = f2bf(g);
}

// ============ K2a: amxB = bf16(V . elu(p_i + qb_j) + bv) ; column sumsq ============
__global__ __launch_bounds__(256) void k2_amx(
    const float* __restrict__ p, const float* __restrict__ qb,
    const float* __restrict__ V, const float* __restrict__ bv,
    unsigned short* __restrict__ amxB, float* __restrict__ colsq)
{
    __shared__ float p_sh[32*36], q_sh[32*36], v_sh[32], sq_sh[32*17];
    int t = threadIdx.x;
    int b = blockIdx.z, i0 = blockIdx.y*32, j0 = blockIdx.x*32;
    {
        int r = t >> 3, c4 = (t & 7)*4;
        *(float4*)&p_sh[r*36 + c4] = *(const float4*)(p  + (size_t)(b*512 + i0 + r)*32 + c4);
        *(float4*)&q_sh[r*36 + c4] = *(const float4*)(qb + (size_t)(b*512 + j0 + r)*32 + c4);
    }
    if (t < 32) v_sh[t] = V[t];
    __syncthreads();

    int ti = t >> 4, tj = t & 15;   // rows {ti, ti+16}, cols {tj, tj+16}
    float bv0 = bv[0];
    float a00 = bv0, a01 = bv0, a10 = bv0, a11 = bv0;
    #pragma unroll
    for (int h = 0; h < 32; ++h) {
        float p0 = p_sh[ti*36 + h], p1 = p_sh[(ti+16)*36 + h];
        float q0 = q_sh[tj*36 + h], q1 = q_sh[(tj+16)*36 + h];
        float vh = v_sh[h];
        float x00 = p0+q0, x01 = p0+q1, x10 = p1+q0, x11 = p1+q1;
        float e00 = x00 > 0.f ? x00 : __expf(x00)-1.f;
        float e01 = x01 > 0.f ? x01 : __expf(x01)-1.f;
        float e10 = x10 > 0.f ? x10 : __expf(x10)-1.f;
        float e11 = x11 > 0.f ? x11 : __expf(x11)-1.f;
        a00 += vh*e00; a01 += vh*e01; a10 += vh*e10; a11 += vh*e11;
    }
    size_t base0 = ((size_t)(b*512 + i0 + ti))*512 + j0;
    size_t base1 = ((size_t)(b*512 + i0 + ti + 16))*512 + j0;
    amxB[base0 + tj]      = f2bf(a00);
    amxB[base0 + tj + 16] = f2bf(a01);
    amxB[base1 + tj]      = f2bf(a10);
    amxB[base1 + tj + 16] = f2bf(a11);

    sq_sh[tj*17 + ti]      = a00*a00 + a10*a10;
    sq_sh[(tj+16)*17 + ti] = a01*a01 + a11*a11;
    __syncthreads();
    if (t < 32) {
        float ssum = 0.f;
        #pragma unroll
        for (int r = 0; r < 16; ++r) ssum += sq_sh[t*17 + r];
        atomicAdd(&colsq[b*512 + j0 + t], ssum);
    }
}

// ============ K2w: WbT[b][j][k] = bf16(Wb[k][j] * invn[b][k]) ============
__global__ __launch_bounds__(256) void k2w_scale(
    const float* __restrict__ Wb, const float* __restrict__ colsq,
    unsigned short* __restrict__ WbT)
{
    __shared__ float tile[64][68];
    int t = threadIdx.x;
    int j0 = blockIdx.x*64, k0 = blockIdx.y*64;
    #pragma unroll
    for (int q = 0; q < 4; ++q) {
        int kr = (t>>4) + 16*q;
        int jc = (t&15)*4;
        *(float4*)&tile[kr][jc] = *(const float4*)(Wb + (size_t)(k0+kr)*512 + j0 + jc);
    }
    __syncthreads();
    int jl = t>>2, kc = (t&3)*16;
    int j = j0 + jl;
    for (int b = 0; b < 4; ++b) {
        ushort8 v0, v1;
        #pragma unroll
        for (int kk = 0; kk < 8; ++kk) {
            float inv = 1.f/fmaxf(sqrtf(colsq[b*512 + k0+kc+kk]), 1e-12f);
            v0[kk] = f2bf(tile[kc+kk][jl] * inv);
        }
        #pragma unroll
        for (int kk = 0; kk < 8; ++kk) {
            float inv = 1.f/fmaxf(sqrtf(colsq[b*512 + k0+kc+8+kk]), 1e-12f);
            v1[kk] = f2bf(tile[kc+8+kk][jl] * inv);
        }
        unsigned short* dst = WbT + ((size_t)(b*512 + j))*512 + k0 + kc;
        *(ushort8*)dst = v0;
        *(ushort8*)(dst+8) = v1;
    }
}

// ============ K3a: S = amxN @ Wb via bf16 MFMA; gate epilogue -> Abf ============
__global__ __launch_bounds__(256) void k3a_mfma(
    const unsigned short* __restrict__ amxB, const unsigned short* __restrict__ WbT,
    const float* __restrict__ colsq, const float* __restrict__ wb,
    const float* __restrict__ adj, unsigned short* __restrict__ Abf)
{
    __shared__ __align__(16) unsigned short As[64*72];   // [row i][k]
    __shared__ __align__(16) unsigned short Bs[64*72];   // [col j][k]
    int t = threadIdx.x;
    int b = blockIdx.z;
    int i0 = blockIdx.y*64, j0 = blockIdx.x*64;
    int wv = t >> 6, lane = t & 63;
    int wr = (wv>>1)*32, wc = (wv&1)*32;
    f32x4 acc[2][2] = {};

    int srow = t >> 2, skc = (t&3)*16;
    const unsigned short* ag = amxB + ((size_t)(b*512 + i0 + srow))*512 + skc;
    const unsigned short* bg = WbT  + ((size_t)(b*512 + j0 + srow))*512 + skc;
    unsigned short* asl = &As[srow*72 + skc];
    unsigned short* bsl = &Bs[srow*72 + skc];

    for (int k0 = 0; k0 < 512; k0 += 64) {
        short8 a0 = *(const short8*)(ag + k0);
        short8 a1 = *(const short8*)(ag + k0 + 8);
        short8 b0 = *(const short8*)(bg + k0);
        short8 b1 = *(const short8*)(bg + k0 + 8);
        *(short8*)asl = a0; *(short8*)(asl+8) = a1;
        *(short8*)bsl = b0; *(short8*)(bsl+8) = b1;
        __syncthreads();
        #pragma unroll
        for (int h = 0; h < 2; ++h) {
            int kk = h*32 + (lane>>4)*8;
            short8 af0 = *(const short8*)&As[(wr +      (lane&15))*72 + kk];
            short8 af1 = *(const short8*)&As[(wr + 16 + (lane&15))*72 + kk];
            short8 bf0 = *(const short8*)&Bs[(wc +      (lane&15))*72 + kk];
            short8 bf1 = *(const short8*)&Bs[(wc + 16 + (lane&15))*72 + kk];
            acc[0][0] = __builtin_amdgcn_mfma_f32_16x16x32_bf16(af0, bf0, acc[0][0],0,0,0);
            acc[0][1] = __builtin_amdgcn_mfma_f32_16x16x32_bf16(af0, bf1, acc[0][1],0,0,0);
            acc[1][0] = __builtin_amdgcn_mfma_f32_16x16x32_bf16(af1, bf0, acc[1][0],0,0,0);
            acc[1][1] = __builtin_amdgcn_mfma_f32_16x16x32_bf16(af1, bf1, acc[1][1],0,0,0);
        }
        __syncthreads();
    }

    float wbs = wb[0];
    #pragma unroll
    for (int fj = 0; fj < 2; ++fj) {
        int j = j0 + wc + fj*16 + (lane&15);
        float inv = 1.f/fmaxf(sqrtf(colsq[b*512 + j]), 1e-12f);
        #pragma unroll
        for (int fi = 0; fi < 2; ++fi)
        #pragma unroll
        for (int r = 0; r < 4; ++r) {
            int i = i0 + wr + fi*16 + (lane>>4)*4 + r;
            float S = acc[fi][fj][r] + wbs;
            float c = 1.f/(1.f + __expf(-S));
            float aN = bf2f(amxB[((size_t)(b*512)+i)*512 + j]) * inv;
            Abf[((size_t)(b*512)+i)*512 + j] = f2bf(adj[i*512+j]*c + aN*(1.f - c));
        }
    }
}

// ============ K3b: xg = relu(Abf@G1 + gc1_b); zT[b][sx][i] = xg@gc2_w ============
#define G1T_STRIDE 536
__global__ __launch_bounds__(256) void k3b_mfma(
    const unsigned short* __restrict__ Abf, const unsigned short* __restrict__ G1bf,
    const float* __restrict__ gc1_b, const float* __restrict__ gc2_w,
    float* __restrict__ zT)
{
    __shared__ __align__(16) unsigned short G1T[64*G1T_STRIDE];  // [c][k=j]
    __shared__ __align__(16) unsigned short As[64*72];           // [i][k]
    __shared__ float xg[64*65];                                   // [i][c]
    int t = threadIdx.x;
    int b = blockIdx.y, i0 = blockIdx.x*64;
    int wv = t >> 6, lane = t & 63;
    int wrow = wv*16;

    // stage G1^T: G1T[c][j] = G1bf[(b*512+j)*64 + c]
    {
        int c = t & 63;
        int jg0 = t >> 6;          // 0..3
        for (int q = 0; q < 16; ++q) {
            int j0 = (jg0 + 4*q)*8;
            ushort8 v;
            #pragma unroll
            for (int jj = 0; jj < 8; ++jj)
                v[jj] = G1bf[((size_t)(b*512) + j0 + jj)*64 + c];
            *(ushort8*)&G1T[c*G1T_STRIDE + j0] = v;
        }
    }

    f32x4 acc[4] = {};
    int srow = t >> 2, skc = (t&3)*16;
    const unsigned short* ag = Abf + ((size_t)(b*512 + i0 + srow))*512 + skc;
    unsigned short* asl = &As[srow*72 + skc];
    __syncthreads();

    for (int k0 = 0; k0 < 512; k0 += 64) {
        short8 a0 = *(const short8*)(ag + k0);
        short8 a1 = *(const short8*)(ag + k0 + 8);
        *(short8*)asl = a0; *(short8*)(asl+8) = a1;
        __syncthreads();
        #pragma unroll
        for (int h = 0; h < 2; ++h) {
            int kk = h*32 + (lane>>4)*8;
            short8 af = *(const short8*)&As[(wrow + (lane&15))*72 + kk];
            #pragma unroll
            for (int cb = 0; cb < 4; ++cb) {
                short8 bfr = *(const short8*)&G1T[(cb*16 + (lane&15))*G1T_STRIDE + k0 + kk];
                acc[cb] = __builtin_amdgcn_mfma_f32_16x16x32_bf16(af, bfr, acc[cb],0,0,0);
            }
        }
        __syncthreads();
    }

    // xg to LDS (relu + bias)
    #pragma unroll
    for (int cb = 0; cb < 4; ++cb) {
        int c = cb*16 + (lane&15);
        float gb = gc1_b[c];
        #pragma unroll
        for (int r = 0; r < 4; ++r) {
            int row = wrow + (lane>>4)*4 + r;
            xg[row*65 + c] = fmaxf(acc[cb][r] + gb, 0.f);
        }
    }
    __syncthreads();

    // z = xg @ gc2_w  -> zT[b][sx][i0+row]
    {
        int rowz = t & 63;
        int sxb = t >> 6;
        #pragma unroll
        for (int kq = 0; kq < 3; ++kq) {
            int sx = sxb + 4*kq;
            if (sx < 10) {
                float a = 0.f;
                #pragma unroll
                for (int c = 0; c < 64; ++c) a += xg[rowz*65 + c]*gc2_w[c*10 + sx];
                zT[((size_t)(b*10) + sx)*512 + i0 + rowz] = a;
            }
        }
    }
}

// ============ K4: out = relu(Abf@zT + gc2_b).out_w + tdot ============
__global__ __launch_bounds__(256) void k4_out(
    const unsigned short* __restrict__ Abf, const float* __restrict__ zT,
    const float* __restrict__ gc2_b, const float* __restrict__ out_w,
    const float* __restrict__ tdot, float* __restrict__ out)
{
    __shared__ float zt_l[5120];
    int t = threadIdx.x;
    int w = t >> 6, lane = t & 63;
    int s = blockIdx.x*4 + w;       // (b,i)
    int b = s >> 9;
    #pragma unroll
    for (int q = 0; q < 20; ++q)
        zt_l[q*256 + t] = zT[(size_t)(b*5120) + q*256 + t];
    __syncthreads();

    const unsigned short* Arow = Abf + (size_t)s*512;
    float acc[10] = {};
    #pragma unroll
    for (int q = 0; q < 8; ++q) {
        int j = q*64 + lane;
        float a = bf2f(Arow[j]);
        #pragma unroll
        for (int sx = 0; sx < 10; ++sx) acc[sx] += a*zt_l[sx*512 + j];
    }
    #pragma unroll
    for (int sx = 0; sx < 10; ++sx)
        #pragma unroll
        for (int off = 32; off; off >>= 1) acc[sx] += __shfl_down(acc[sx], off);
    if (lane == 0) {
        float o = tdot[s];
        #pragma unroll
        for (int sx = 0; sx < 10; ++sx)
            o += fmaxf(acc[sx] + gc2_b[sx], 0.f) * out_w[sx];
        out[s] = o;
    }
}

extern "C" void kernel_launch(void* const* d_in, const int* in_sizes, int n_in,
                              void* d_out, int out_size, void* d_ws, size_t ws_size,
                              hipStream_t stream) {
    const float* x       = (const float*)d_in[0];
    const float* W_ih    = (const float*)d_in[1];
    const float* W_hh    = (const float*)d_in[2];
    const float* b_ih    = (const float*)d_in[3];
    const float* b_hh    = (const float*)d_in[4];
    const float* W1      = (const float*)d_in[5];
    const float* b1      = (const float*)d_in[6];
    const float* W2      = (const float*)d_in[7];
    const float* V       = (const float*)d_in[8];
    const float* bv      = (const float*)d_in[9];
    const float* Wb      = (const float*)d_in[10];
    const float* wb      = (const float*)d_in[11];
    const float* conv_w  = (const float*)d_in[12];
    const float* conv_b  = (const float*)d_in[13];
    const float* convl_w = (const float*)d_in[14];
    const float* convl_b = (const float*)d_in[15];
    const float* gc1_w   = (const float*)d_in[16];
    const float* gc1_b   = (const float*)d_in[17];
    const float* gc2_w   = (const float*)d_in[18];
    const float* gc2_b   = (const float*)d_in[19];
    const float* out_w   = (const float*)d_in[20];
    const float* out_b   = (const float*)d_in[21];
    const float* adj     = (const float*)d_in[22];

    float* ws    = (float*)d_ws;
    float* p     = ws + OFF_P;
    float* qb    = ws + OFF_QB;
    float* tdot  = ws + OFF_TDOT;
    float* colsq = ws + OFF_COLSQ;
    float* zT    = ws + OFF_ZT;
    unsigned short* G1bf = (unsigned short*)(ws + OFF_G1B);
    unsigned short* amxB = (unsigned short*)(ws + OFF_AMXB);
    unsigned short* WbT  = (unsigned short*)(ws + OFF_WBT);
    unsigned short* Abf  = (unsigned short*)(ws + OFF_ABF);
    float* out   = (float*)d_out;

    k1_rnn<<<dim3(512), dim3(256), 0, stream>>>(
        x, W_ih, W_hh, b_ih, b_hh, W1, b1, W2,
        conv_w, conv_b, convl_w, convl_b, gc1_w, out_w, out_b,
        p, qb, G1bf, tdot, colsq);

    k2_amx<<<dim3(16,16,4), dim3(256), 0, stream>>>(p, qb, V, bv, amxB, colsq);
    k2w_scale<<<dim3(8,8), dim3(256), 0, stream>>>(Wb, colsq, WbT);

    k3a_mfma<<<dim3(8,8,4), dim3(256), 0, stream>>>(amxB, WbT, colsq, wb, adj, Abf);
    k3b_mfma<<<dim3(8,4), dim3(256), 0, stream>>>(Abf, G1bf, gc1_b, gc2_w, zT);
    k4_out<<<dim3(512), dim3(256), 0, stream>>>(Abf, zT, gc2_b, out_w, tdot, out);
}